// Round 10
// baseline (77.748 us; speedup 1.0000x reference)
//
#include <hip/hip_runtime.h>
#include <math.h>

// FreqEmbedding: seq [16,512,64] f32 -> out [16,512,65,64] f32
// reflect-pad(64) -> hanning(128) frames -> rfft(128) -> complex standardize
// over (L,F) per (B,C) -> abs.
//
// Pass 0 (pad): materialize reflect-padded input [16,640,64] (proven).
// Pass A (reduce): Parseval + symmetry identities (4 dot products) (proven).
// Pass B (write): radix-2 DIF PHASE-SPLIT monolithic FFT. Phase 1:
//   U=FFT32(z[p]+z[p+32]) -> even bins {0..64}; Phase 2 (reload):
//   V=FFT32((z[p]-z[p+32])*W64^p) -> odd bins. The rfft unpack coupling
//   k<->64-k preserves parity, so each phase is self-contained. Live state
//   = 32 complex (64 f32) + temps ~= 105 VGPR, vs 128+temps before ->
//   R4-R9 lesson: every 128-f32-state variant parked ~180 total regs ->
//   2 waves/SIMD, dep-latency-bound (VALUBusy 31-38%). This halves state
//   with zero duplicated work, zero shfl, zero divergent selects.

#define B_ 16
#define L_ 512
#define C_ 64
#define W_ 128
#define F_ 65
#define LP 640  // padded length
#define NLF (L_ * F_)  // 33280

// ---------- compile-time trig tables (fold to VALU literals) ----------
constexpr double kPI = 3.14159265358979323846;

constexpr double csin_(double x) {
  while (x > kPI) x -= 2.0 * kPI;
  while (x < -kPI) x += 2.0 * kPI;
  double t = x, s = x, x2 = x * x;
  for (int i = 1; i <= 24; ++i) {
    t *= -x2 / ((2.0 * i) * (2.0 * i + 1.0));
    s += t;
  }
  return s;
}
constexpr double ccos_(double x) { return csin_(kPI / 2.0 - x); }

constexpr int bitrev5(int n) {
  int r = 0;
  for (int i = 0; i < 5; ++i) r |= ((n >> i) & 1) << (4 - i);
  return r;
}

struct Tables {
  float win[128];           // hanning w_n
  float walt[128];          // (-1)^n w_n
  float w2[128];            // w_n^2
  float wg[128];            // w_n * G_n
  float t32r[16], t32i[16]; // exp(-2*pi*i*r/32)
  float e64r[32], e64i[32]; // exp(-2*pi*i*p/64)
  float c128r[33], c128i[33]; // exp(-2*pi*i*k/128)
  constexpr Tables()
      : win(), walt(), w2(), wg(), t32r(), t32i(), e64r(), e64i(), c128r(), c128i() {
    for (int n = 0; n < 128; ++n) {
      const double wd = 0.5 - 0.5 * ccos_(2.0 * kPI * n / 127.0);
      win[n] = (float)wd;
      walt[n] = (n & 1) ? (float)(-wd) : (float)wd;
      w2[n] = (float)(wd * wd);
      if (n == 0) {
        wg[n] = 0.0f;
      } else {
        const double G = csin_(kPI * n / 2.0) * csin_(65.0 * kPI * n / 128.0) /
                         csin_(kPI * n / 128.0);
        wg[n] = (float)(wd * G);
      }
    }
    for (int r = 0; r < 16; ++r) {
      t32r[r] = (float)ccos_(2.0 * kPI * r / 32.0);
      t32i[r] = (float)(-csin_(2.0 * kPI * r / 32.0));
    }
    for (int p = 0; p < 32; ++p) {
      e64r[p] = (float)ccos_(2.0 * kPI * p / 64.0);
      e64i[p] = (float)(-csin_(2.0 * kPI * p / 64.0));
    }
    for (int k = 0; k <= 32; ++k) {
      c128r[k] = (float)ccos_(2.0 * kPI * k / 128.0);
      c128i[k] = (float)(-csin_(2.0 * kPI * k / 128.0));
    }
  }
};
constexpr Tables TBL{};

// branchless reflect into [0,512) for t in [-64, 575]
__device__ __forceinline__ int refl(int t) {
  const int a = max(t, -t);
  return min(a, 1022 - a);
}

__device__ __forceinline__ float fast_sqrt(float x) {
  float r;
  asm("v_sqrt_f32 %0, %1" : "=v"(r) : "v"(x));
  return r;
}

// ---------------- Pass 0: materialize reflect-padded input ----------------
__global__ void __launch_bounds__(256)
fe_pad_kernel(const float* __restrict__ seq, float* __restrict__ pad) {
  const int idx = blockIdx.x * 256 + threadIdx.x;  // b*LP*C + t*C + c
  const int c = idx & 63;
  const int row = idx >> 6;  // b*LP + t
  const int b = row / LP;
  const int t = row - b * LP;
  const int s = refl(t - 64);
  pad[idx] = seq[(b * L_ + s) * C_ + c];
}

// ws layout (floats): [0..1023] sum_re, [1024..2047] sum_im, [2048..3071] sum_sq,
//                     [4096 ..] padded input [16][640][64]
// ---------------- Pass A: Parseval reduce (on padded input) ----------------
__global__ void __launch_bounds__(256)
fe_reduce_kernel(const float* __restrict__ pad, float* __restrict__ acc) {
  const int p = blockIdx.x * 4 + (threadIdx.x >> 6);
  const int b = __builtin_amdgcn_readfirstlane(p >> 9);
  const int l = __builtin_amdgcn_readfirstlane(p & (L_ - 1));
  const int c = threadIdx.x & 63;

  const float* base = pad + ((size_t)(b * LP + l)) * C_ + c;

  float x0 = 0.f, x64 = 0.f, p2 = 0.f, d2 = 0.f;
#pragma unroll
  for (int n = 0; n < 128; ++n) {
    const float v = base[n * C_];
    x0 += TBL.win[n] * v;
    x64 += TBL.walt[n] * v;
    const float wv = TBL.w2[n] * v;
    p2 += wv * v;
    d2 += TBL.wg[n] * v;
  }

  const float sre = 0.5f * (x0 + x64);
  const float sim = -d2;
  const float ssq = 64.0f * p2 + 0.5f * (x0 * x0 + x64 * x64);

  __shared__ float red[3][256];
  const int tid = threadIdx.x;
  red[0][tid] = sre;
  red[1][tid] = sim;
  red[2][tid] = ssq;
  __syncthreads();
  if (tid < 64) {
    const float a0 = red[0][tid] + red[0][tid + 64] + red[0][tid + 128] + red[0][tid + 192];
    const float a1 = red[1][tid] + red[1][tid + 64] + red[1][tid + 128] + red[1][tid + 192];
    const float a2 = red[2][tid] + red[2][tid + 64] + red[2][tid + 128] + red[2][tid + 192];
    const int g = b * C_ + tid;
    unsafeAtomicAdd(&acc[g], a0);
    unsafeAtomicAdd(&acc[1024 + g], a1);
    unsafeAtomicAdd(&acc[2048 + g], a2);
  }
}

// 32-pt complex DIT FFT, in-place, input in bitrev5 order, literal twiddles
__device__ __forceinline__ void fft32(float* __restrict__ ur, float* __restrict__ ui) {
#pragma unroll
  for (int s = 0; s < 5; ++s) {
    const int half = 1 << s;
    const int len = half << 1;
#pragma unroll
    for (int j = 0; j < half; ++j) {
      const float wr = TBL.t32r[j << (4 - s)];
      const float wi = TBL.t32i[j << (4 - s)];
#pragma unroll
      for (int base2 = 0; base2 < 32; base2 += len) {
        const int a = base2 + j;
        const int b2 = a + half;
        const float tr = wr * ur[b2] - wi * ui[b2];
        const float ti = wr * ui[b2] + wi * ur[b2];
        ur[b2] = ur[a] - tr;
        ui[b2] = ui[a] - ti;
        ur[a] += tr;
        ui[a] += ti;
      }
    }
  }
}

// ---------------- Pass B: DIF phase-split FFT + write ----------------
__global__ void __launch_bounds__(256, 4)
fe_write_kernel(const float* __restrict__ pad, const float* __restrict__ acc,
                float* __restrict__ out) {
  const int tid = threadIdx.x;
  const int p = blockIdx.x * 4 + (tid >> 6);
  const int b = __builtin_amdgcn_readfirstlane(p >> 9);
  const int l = __builtin_amdgcn_readfirstlane(p & (L_ - 1));
  const int c = tid & 63;

  // fused finalize: true-scale sums -> constants matching the 2x bins
  const int g = b * C_ + c;
  const float invN = 1.0f / (float)NLF;
  const float sr = acc[g] * invN;
  const float si = acc[1024 + g] * invN;
  const float qq = acc[2048 + g] * invN;
  const float var = qq - sr * sr - si * si;
  const float mr = 2.0f * sr;
  const float mi = 2.0f * si;
  const float is = 0.5f * rsqrtf(var);

  const float* base = pad + ((size_t)(b * LP + l)) * C_ + c;
  float* obase = out + (((size_t)(b * L_ + l)) * F_) * C_ + c;

  auto emit = [&](int f, float Xr, float Xi) {
    const float dr = Xr - mr;
    const float di = Xi - mi;
    const float amp = fast_sqrt(__builtin_fmaf(dr, dr, di * di)) * is;
    __builtin_nontemporal_store(amp, &obase[(size_t)f * C_]);
  };

  float ur[32], ui[32];

  // ================= Phase 1: EVEN bins (0,2,...,64) =================
  // u[p] = z[p] + z[p+32]; U = FFT32(u); Z[2t] = U[t]
#pragma unroll
  for (int j = 0; j < 32; ++j) {
    const int q = bitrev5(j);
    const float a0 = TBL.win[2 * q] * base[(2 * q) * C_];
    const float a1 = TBL.win[2 * q + 1] * base[(2 * q + 1) * C_];
    const float b0 = TBL.win[2 * q + 64] * base[(2 * q + 64) * C_];
    const float b1 = TBL.win[2 * q + 65] * base[(2 * q + 65) * C_];
    ur[j] = a0 + b0;
    ui[j] = a1 + b1;
  }
  fft32(ur, ui);

  emit(0, 2.0f * (ur[0] + ui[0]), 0.0f);
  emit(64, 2.0f * (ur[0] - ui[0]), 0.0f);
  emit(32, 2.0f * ur[16], -2.0f * ui[16]);
#pragma unroll
  for (int t = 1; t < 16; ++t) {
    const int u2 = 32 - t;  // partner slot: Z[64-2t] = U[32-t]
    const float cr = TBL.c128r[2 * t], ci = TBL.c128i[2 * t];
    const float Er = ur[t] + ur[u2];
    const float Ei = ui[t] - ui[u2];
    const float Or = ui[t] + ui[u2];
    const float Oi = ur[u2] - ur[t];
    const float wOr = cr * Or - ci * Oi;
    const float wOi = cr * Oi + ci * Or;
    emit(2 * t, Er + wOr, Ei + wOi);
    emit(64 - 2 * t, Er - wOr, wOi - Ei);
  }

  // ================= Phase 2: ODD bins (1,3,...,63) =================
  // v[p] = (z[p] - z[p+32]) * W64^p; V = FFT32(v); Z[2t+1] = V[t]
#pragma unroll
  for (int j = 0; j < 32; ++j) {
    const int q = bitrev5(j);
    const float a0 = TBL.win[2 * q] * base[(2 * q) * C_];
    const float a1 = TBL.win[2 * q + 1] * base[(2 * q + 1) * C_];
    const float b0 = TBL.win[2 * q + 64] * base[(2 * q + 64) * C_];
    const float b1 = TBL.win[2 * q + 65] * base[(2 * q + 65) * C_];
    const float vr = a0 - b0;
    const float vi = a1 - b1;
    ur[j] = TBL.e64r[q] * vr - TBL.e64i[q] * vi;
    ui[j] = TBL.e64r[q] * vi + TBL.e64i[q] * vr;
  }
  fft32(ur, ui);

#pragma unroll
  for (int t = 0; t < 16; ++t) {
    const int u2 = 31 - t;  // partner slot: Z[64-(2t+1)] = V[31-t]
    const float cr = TBL.c128r[2 * t + 1], ci = TBL.c128i[2 * t + 1];
    const float Er = ur[t] + ur[u2];
    const float Ei = ui[t] - ui[u2];
    const float Or = ui[t] + ui[u2];
    const float Oi = ur[u2] - ur[t];
    const float wOr = cr * Or - ci * Oi;
    const float wOi = cr * Oi + ci * Or;
    emit(2 * t + 1, Er + wOr, Ei + wOi);
    emit(63 - 2 * t, Er - wOr, wOi - Ei);
  }
}

extern "C" void kernel_launch(void* const* d_in, const int* in_sizes, int n_in,
                              void* d_out, int out_size, void* d_ws, size_t ws_size,
                              hipStream_t stream) {
  const float* seq = (const float*)d_in[0];
  float* out = (float*)d_out;
  float* ws = (float*)d_ws;
  float* acc = ws;          // 3072 floats
  float* pad = ws + 4096;   // 16*640*64 = 655360 floats (2.62 MB)

  hipMemsetAsync(acc, 0, 3072 * sizeof(float), stream);

  fe_pad_kernel<<<(B_ * LP * C_) / 256, 256, 0, stream>>>(seq, pad);
  fe_reduce_kernel<<<(B_ * L_) / 4, 256, 0, stream>>>(pad, acc);
  fe_write_kernel<<<(B_ * L_) / 4, 256, 0, stream>>>(pad, acc, out);
}

// Round 11
// 72.836 us; speedup vs baseline: 1.0674x; 1.0674x over previous
//
#include <hip/hip_runtime.h>
#include <math.h>

// FreqEmbedding: seq [16,512,64] f32 -> out [16,512,65,64] f32
// reflect-pad(64) -> hanning(128) frames -> rfft(128) -> complex standardize
// over (L,F) per (B,C) -> abs.
//
// Pass 0 (pad): materialize reflect-padded input [16,640,64] (proven).
// Pass A (reduce): Parseval + symmetry identities (4 dot products) (proven).
// Pass B/C (write): radix-2 DIF phase split, ONE KERNEL PER PHASE.
//   even: U=FFT32(z[p]+z[p+32]) -> bins {0,2,..,64}
//   odd:  V=FFT32((z[p]-z[p+32])*W64^p) -> bins {1,3,..,63}
//   (rfft unpack coupling k<->64-k preserves parity -> phases independent.)
//   R4-R10 lesson: any single allocation needing >128 regs => 2 waves/SIMD
//   (AGPR parking) or scratch spill. Separate kernels keep each phase at
//   ~64-f32 state + temps ~ 100 VGPR NATURAL allocation -> ~5 waves/SIMD,
//   single compact body each, no divergence/shfl/selects. Extra cost: the
//   128 window-loads run twice (L1/L2-hit; pad = 2.6 MB resident).

#define B_ 16
#define L_ 512
#define C_ 64
#define W_ 128
#define F_ 65
#define LP 640  // padded length
#define NLF (L_ * F_)  // 33280

// ---------- compile-time trig tables (fold to VALU literals) ----------
constexpr double kPI = 3.14159265358979323846;

constexpr double csin_(double x) {
  while (x > kPI) x -= 2.0 * kPI;
  while (x < -kPI) x += 2.0 * kPI;
  double t = x, s = x, x2 = x * x;
  for (int i = 1; i <= 24; ++i) {
    t *= -x2 / ((2.0 * i) * (2.0 * i + 1.0));
    s += t;
  }
  return s;
}
constexpr double ccos_(double x) { return csin_(kPI / 2.0 - x); }

constexpr int bitrev5(int n) {
  int r = 0;
  for (int i = 0; i < 5; ++i) r |= ((n >> i) & 1) << (4 - i);
  return r;
}

struct Tables {
  float win[128];           // hanning w_n
  float walt[128];          // (-1)^n w_n
  float w2[128];            // w_n^2
  float wg[128];            // w_n * G_n
  float t32r[16], t32i[16]; // exp(-2*pi*i*r/32)
  float e64r[32], e64i[32]; // exp(-2*pi*i*p/64)
  float c128r[33], c128i[33]; // exp(-2*pi*i*k/128)
  constexpr Tables()
      : win(), walt(), w2(), wg(), t32r(), t32i(), e64r(), e64i(), c128r(), c128i() {
    for (int n = 0; n < 128; ++n) {
      const double wd = 0.5 - 0.5 * ccos_(2.0 * kPI * n / 127.0);
      win[n] = (float)wd;
      walt[n] = (n & 1) ? (float)(-wd) : (float)wd;
      w2[n] = (float)(wd * wd);
      if (n == 0) {
        wg[n] = 0.0f;
      } else {
        const double G = csin_(kPI * n / 2.0) * csin_(65.0 * kPI * n / 128.0) /
                         csin_(kPI * n / 128.0);
        wg[n] = (float)(wd * G);
      }
    }
    for (int r = 0; r < 16; ++r) {
      t32r[r] = (float)ccos_(2.0 * kPI * r / 32.0);
      t32i[r] = (float)(-csin_(2.0 * kPI * r / 32.0));
    }
    for (int p = 0; p < 32; ++p) {
      e64r[p] = (float)ccos_(2.0 * kPI * p / 64.0);
      e64i[p] = (float)(-csin_(2.0 * kPI * p / 64.0));
    }
    for (int k = 0; k <= 32; ++k) {
      c128r[k] = (float)ccos_(2.0 * kPI * k / 128.0);
      c128i[k] = (float)(-csin_(2.0 * kPI * k / 128.0));
    }
  }
};
constexpr Tables TBL{};

// branchless reflect into [0,512) for t in [-64, 575]
__device__ __forceinline__ int refl(int t) {
  const int a = max(t, -t);
  return min(a, 1022 - a);
}

__device__ __forceinline__ float fast_sqrt(float x) {
  float r;
  asm("v_sqrt_f32 %0, %1" : "=v"(r) : "v"(x));
  return r;
}

// ---------------- Pass 0: materialize reflect-padded input ----------------
__global__ void __launch_bounds__(256)
fe_pad_kernel(const float* __restrict__ seq, float* __restrict__ pad) {
  const int idx = blockIdx.x * 256 + threadIdx.x;  // b*LP*C + t*C + c
  const int c = idx & 63;
  const int row = idx >> 6;  // b*LP + t
  const int b = row / LP;
  const int t = row - b * LP;
  const int s = refl(t - 64);
  pad[idx] = seq[(b * L_ + s) * C_ + c];
}

// ws layout (floats): [0..1023] sum_re, [1024..2047] sum_im, [2048..3071] sum_sq,
//                     [4096 ..] padded input [16][640][64]
// ---------------- Pass A: Parseval reduce (on padded input) ----------------
__global__ void __launch_bounds__(256)
fe_reduce_kernel(const float* __restrict__ pad, float* __restrict__ acc) {
  const int p = blockIdx.x * 4 + (threadIdx.x >> 6);
  const int b = __builtin_amdgcn_readfirstlane(p >> 9);
  const int l = __builtin_amdgcn_readfirstlane(p & (L_ - 1));
  const int c = threadIdx.x & 63;

  const float* base = pad + ((size_t)(b * LP + l)) * C_ + c;

  float x0 = 0.f, x64 = 0.f, p2 = 0.f, d2 = 0.f;
#pragma unroll
  for (int n = 0; n < 128; ++n) {
    const float v = base[n * C_];
    x0 += TBL.win[n] * v;
    x64 += TBL.walt[n] * v;
    const float wv = TBL.w2[n] * v;
    p2 += wv * v;
    d2 += TBL.wg[n] * v;
  }

  const float sre = 0.5f * (x0 + x64);
  const float sim = -d2;
  const float ssq = 64.0f * p2 + 0.5f * (x0 * x0 + x64 * x64);

  __shared__ float red[3][256];
  const int tid = threadIdx.x;
  red[0][tid] = sre;
  red[1][tid] = sim;
  red[2][tid] = ssq;
  __syncthreads();
  if (tid < 64) {
    const float a0 = red[0][tid] + red[0][tid + 64] + red[0][tid + 128] + red[0][tid + 192];
    const float a1 = red[1][tid] + red[1][tid + 64] + red[1][tid + 128] + red[1][tid + 192];
    const float a2 = red[2][tid] + red[2][tid + 64] + red[2][tid + 128] + red[2][tid + 192];
    const int g = b * C_ + tid;
    unsafeAtomicAdd(&acc[g], a0);
    unsafeAtomicAdd(&acc[1024 + g], a1);
    unsafeAtomicAdd(&acc[2048 + g], a2);
  }
}

// 32-pt complex DIT FFT, in-place, input in bitrev5 order, literal twiddles
__device__ __forceinline__ void fft32(float* __restrict__ ur, float* __restrict__ ui) {
#pragma unroll
  for (int s = 0; s < 5; ++s) {
    const int half = 1 << s;
    const int len = half << 1;
#pragma unroll
    for (int j = 0; j < half; ++j) {
      const float wr = TBL.t32r[j << (4 - s)];
      const float wi = TBL.t32i[j << (4 - s)];
#pragma unroll
      for (int base2 = 0; base2 < 32; base2 += len) {
        const int a = base2 + j;
        const int b2 = a + half;
        const float tr = wr * ur[b2] - wi * ui[b2];
        const float ti = wr * ui[b2] + wi * ur[b2];
        ur[b2] = ur[a] - tr;
        ui[b2] = ui[a] - ti;
        ur[a] += tr;
        ui[a] += ti;
      }
    }
  }
}

// common prologue: thread -> (b, l, c), mu/sigma constants
#define FE_PROLOGUE                                                            \
  const int tid = threadIdx.x;                                                 \
  const int p = blockIdx.x * 4 + (tid >> 6);                                   \
  const int b = __builtin_amdgcn_readfirstlane(p >> 9);                        \
  const int l = __builtin_amdgcn_readfirstlane(p & (L_ - 1));                  \
  const int c = tid & 63;                                                      \
  const int g = b * C_ + c;                                                    \
  const float invN = 1.0f / (float)NLF;                                        \
  const float sr = acc[g] * invN;                                              \
  const float si = acc[1024 + g] * invN;                                       \
  const float qq = acc[2048 + g] * invN;                                       \
  const float var = qq - sr * sr - si * si;                                    \
  const float mr = 2.0f * sr;                                                  \
  const float mi = 2.0f * si;                                                  \
  const float is = 0.5f * rsqrtf(var);                                         \
  const float* base = pad + ((size_t)(b * LP + l)) * C_ + c;                   \
  float* obase = out + (((size_t)(b * L_ + l)) * F_) * C_ + c;                 \
  auto emit = [&](int f, float Xr, float Xi) {                                 \
    const float dr = Xr - mr;                                                  \
    const float di = Xi - mi;                                                  \
    const float amp = fast_sqrt(__builtin_fmaf(dr, dr, di * di)) * is;         \
    __builtin_nontemporal_store(amp, &obase[(size_t)f * C_]);                  \
  };

// ---------------- Pass B: EVEN bins (0,2,...,64) ----------------
__global__ void __launch_bounds__(256)
fe_write_even(const float* __restrict__ pad, const float* __restrict__ acc,
              float* __restrict__ out) {
  FE_PROLOGUE
  float ur[32], ui[32];
  // u[p] = z[p] + z[p+32]; U = FFT32(u); Z[2t] = U[t]
#pragma unroll
  for (int j = 0; j < 32; ++j) {
    const int q = bitrev5(j);
    ur[j] = __builtin_fmaf(TBL.win[2 * q + 64], base[(2 * q + 64) * C_],
                           TBL.win[2 * q] * base[(2 * q) * C_]);
    ui[j] = __builtin_fmaf(TBL.win[2 * q + 65], base[(2 * q + 65) * C_],
                           TBL.win[2 * q + 1] * base[(2 * q + 1) * C_]);
  }
  fft32(ur, ui);

  emit(0, 2.0f * (ur[0] + ui[0]), 0.0f);
  emit(64, 2.0f * (ur[0] - ui[0]), 0.0f);
  emit(32, 2.0f * ur[16], -2.0f * ui[16]);
#pragma unroll
  for (int t = 1; t < 16; ++t) {
    const int u2 = 32 - t;  // Z[64-2t] = U[32-t]
    const float cr = TBL.c128r[2 * t], ci = TBL.c128i[2 * t];
    const float Er = ur[t] + ur[u2];
    const float Ei = ui[t] - ui[u2];
    const float Or = ui[t] + ui[u2];
    const float Oi = ur[u2] - ur[t];
    const float wOr = cr * Or - ci * Oi;
    const float wOi = cr * Oi + ci * Or;
    emit(2 * t, Er + wOr, Ei + wOi);
    emit(64 - 2 * t, Er - wOr, wOi - Ei);
  }
}

// ---------------- Pass C: ODD bins (1,3,...,63) ----------------
__global__ void __launch_bounds__(256)
fe_write_odd(const float* __restrict__ pad, const float* __restrict__ acc,
             float* __restrict__ out) {
  FE_PROLOGUE
  float ur[32], ui[32];
  // v[p] = (z[p] - z[p+32]) * W64^p; V = FFT32(v); Z[2t+1] = V[t]
#pragma unroll
  for (int j = 0; j < 32; ++j) {
    const int q = bitrev5(j);
    const float vr = TBL.win[2 * q] * base[(2 * q) * C_] -
                     TBL.win[2 * q + 64] * base[(2 * q + 64) * C_];
    const float vi = TBL.win[2 * q + 1] * base[(2 * q + 1) * C_] -
                     TBL.win[2 * q + 65] * base[(2 * q + 65) * C_];
    ur[j] = TBL.e64r[q] * vr - TBL.e64i[q] * vi;
    ui[j] = TBL.e64r[q] * vi + TBL.e64i[q] * vr;
  }
  fft32(ur, ui);

#pragma unroll
  for (int t = 0; t < 16; ++t) {
    const int u2 = 31 - t;  // Z[64-(2t+1)] = V[31-t]
    const float cr = TBL.c128r[2 * t + 1], ci = TBL.c128i[2 * t + 1];
    const float Er = ur[t] + ur[u2];
    const float Ei = ui[t] - ui[u2];
    const float Or = ui[t] + ui[u2];
    const float Oi = ur[u2] - ur[t];
    const float wOr = cr * Or - ci * Oi;
    const float wOi = cr * Oi + ci * Or;
    emit(2 * t + 1, Er + wOr, Ei + wOi);
    emit(63 - 2 * t, Er - wOr, wOi - Ei);
  }
}

extern "C" void kernel_launch(void* const* d_in, const int* in_sizes, int n_in,
                              void* d_out, int out_size, void* d_ws, size_t ws_size,
                              hipStream_t stream) {
  const float* seq = (const float*)d_in[0];
  float* out = (float*)d_out;
  float* ws = (float*)d_ws;
  float* acc = ws;          // 3072 floats
  float* pad = ws + 4096;   // 16*640*64 = 655360 floats (2.62 MB)

  hipMemsetAsync(acc, 0, 3072 * sizeof(float), stream);

  fe_pad_kernel<<<(B_ * LP * C_) / 256, 256, 0, stream>>>(seq, pad);
  const int nblocks = (B_ * L_) / 4;
  fe_reduce_kernel<<<nblocks, 256, 0, stream>>>(pad, acc);
  fe_write_even<<<nblocks, 256, 0, stream>>>(pad, acc, out);
  fe_write_odd<<<nblocks, 256, 0, stream>>>(pad, acc, out);
}